// Round 1
// 65.798 us; speedup vs baseline: 1.0064x; 1.0064x over previous
//
#include <hip/hip_runtime.h>

#define NTOK 16384   // B*T = 4*4096
#define BQ 4
#define TQ 4096
#define SQ 8192
#define BLK 1024
#define NBLK 16

typedef unsigned long long u64;

__device__ __forceinline__ unsigned score_key(float s) {
    unsigned u = __float_as_uint(s);
    if ((u << 1) == 0u) u = 0u;                 // -0.0 == +0.0
    return (u & 0x80000000u) ? ~u : (u | 0x80000000u);
}

// Every block redundantly computes the exact top-K threshold over packed
// P = (key << 14) | (16383 - idx)  (all distinct -> no tie-break), then writes
// its own 1/16 output slice. Zero inter-block synchronization.
// Output is fused into wave B: that wave's threads still hold their 16 keys in
// registers, and cand/tok are preloaded at kernel start so no cold load sits
// on the post-threshold critical path.
__global__ __launch_bounds__(BLK) void token_update_kernel(
    const float* __restrict__ scores,
    const int* __restrict__ cand,
    const int* __restrict__ tok,
    const int* __restrict__ bids,
    const int* __restrict__ kptr,
    int* __restrict__ out0,
    int* __restrict__ out1)
{
    __shared__ int h0[1024 * 8];      // 32 KB: level-0, 8 slots/bin
    __shared__ int h1[1024];          // 4 KB: refinement hist
    __shared__ int wtot[16], wsuf[16];
    __shared__ u64 s_pref;
    __shared__ int s_krem, s_E;

    const int tid  = threadIdx.x;
    const int B    = blockIdx.x;
    const int lane = tid & 63;
    const int w    = tid >> 6;

    // ---- critical-path loads first: scalar K, then all 16 keys ----
    const int K = kptr[0];

    const float4* s4 = (const float4*)scores;
    float4 f0 = s4[0 * BLK + tid];
    float4 f1 = s4[1 * BLK + tid];
    float4 f2 = s4[2 * BLK + tid];
    float4 f3 = s4[3 * BLK + tid];

    // ---- output-wave preload: wave B owns this block's output slice ----
    // i4 = c*1024 + tid for tid in [64B, 64B+64): exactly the elements whose
    // keys this thread converts below. Issued now -> hides under selection.
    const bool owave = (w == B);
    int4 c4[4], t4[4];
    if (owave) {
        #pragma unroll
        for (int c = 0; c < 4; ++c) {
            c4[c] = ((const int4*)cand)[c * BLK + tid];
            t4[c] = ((const int4*)tok)[c * BLK + tid];
        }
    }

    // ---- bids non-window copy (independent; off the critical path) ----
    if (tid < 512) {
        int g   = B * 512 + tid;              // [0, 8192) int4 units
        int o4  = g << 2;
        int cc  = o4 >> 12;                   // chunk 0..7 (4096 ints)
        int b   = cc & 3, plane = cc >> 2;
        int off = o4 & 4095;
        int addr = plane ? (BQ * SQ + b * SQ + TQ + off) : (b * SQ + off);
        *(int4*)(out1 + addr) = *(const int4*)(bids + addr);
    }

    const bool none = (K <= 0), all = (K >= NTOK);
    const bool run  = !none && !all;          // uniform across block

    // ---- zero LDS ----
    *(int4*)&h0[tid * 8]     = make_int4(0, 0, 0, 0);
    *(int4*)&h0[tid * 8 + 4] = make_int4(0, 0, 0, 0);
    h1[tid] = 0;
    if (tid == 0) { s_pref = 0ull; s_krem = 1; s_E = 1; }

    // ---- key conversion (loads have had time to land) ----
    unsigned key[16];
    key[ 0] = score_key(f0.x); key[ 1] = score_key(f0.y);
    key[ 2] = score_key(f0.z); key[ 3] = score_key(f0.w);
    key[ 4] = score_key(f1.x); key[ 5] = score_key(f1.y);
    key[ 6] = score_key(f1.z); key[ 7] = score_key(f1.w);
    key[ 8] = score_key(f2.x); key[ 9] = score_key(f2.y);
    key[10] = score_key(f2.z); key[11] = score_key(f2.w);
    key[12] = score_key(f3.x); key[13] = score_key(f3.y);
    key[14] = score_key(f3.z); key[15] = score_key(f3.w);

    __syncthreads();

    u64 pref = 0ull;
    int rb = 36;

    if (run) {
        // ---- level-0 histogram: top 10 key bits, 8 slots ----
        const int slot = tid & 7;
        #pragma unroll
        for (int j = 0; j < 16; ++j)
            atomicAdd(&h0[(key[j] >> 22) * 8 + slot], 1);
        __syncthreads();

        // P-domain shifts: P = (key << 14) | (16383 - idx), 46 bits total.
        const int SH[5]   = {36, 26, 16, 6, 0};
        const int BITS[5] = {10, 10, 10, 10, 6};
        int krem = K, E = 0;

        for (int L = 0; L < 5; ++L) {
            // my bin's count; fold h1 zeroing into the read (same address)
            int c;
            if (L == 0) {
                int4 a = *(int4*)&h0[tid * 8];
                int4 b = *(int4*)&h0[tid * 8 + 4];
                c = a.x + a.y + a.z + a.w + b.x + b.y + b.z + b.w;
            } else {
                c = h1[tid];
                h1[tid] = 0;
            }
            // block-wide suffix scan over 1024 bins (1 bin/thread)
            int incl = c;
            #pragma unroll
            for (int off = 1; off < 64; off <<= 1) {
                int o = __shfl_down(incl, off, 64);
                if (lane + off < 64) incl += o;
            }
            if (lane == 0) wtot[w] = incl;
            __syncthreads();
            if (tid < 16) {
                int v = wtot[tid], i2 = v;
                #pragma unroll
                for (int off = 1; off < 16; off <<= 1) {
                    int o = __shfl_down(i2, off, 64);
                    if (tid + off < 16) i2 += o;
                }
                wsuf[tid] = i2 - v;            // sum of waves strictly after
            }
            __syncthreads();
            int suf = (incl - c) + wsuf[w];    // elements strictly above my bin
            int n   = suf + c;
            if (n >= krem && suf < krem) {
                s_pref = (pref << BITS[L]) | (unsigned)tid;
                s_krem = krem - suf; s_E = c;
            }
            __syncthreads();
            pref = s_pref; krem = s_krem; E = s_E; rb = SH[L];
            if (krem == E || L == 4) break;    // boundary bin fully selected

            // next-level histogram over boundary-bin survivors
            const int nsh = SH[L + 1], nbits = BITS[L + 1];
            #pragma unroll
            for (int j = 0; j < 16; ++j) {
                int i = (((j >> 2) * BLK + tid) << 2) | (j & 3);
                u64 P = ((u64)key[j] << 14) | (unsigned)(NTOK - 1 - i);
                if ((P >> (nsh + nbits)) == pref)
                    atomicAdd(&h1[(int)((P >> nsh) & ((1 << nbits) - 1))], 1);
            }
            __syncthreads();
        }
    }

    const u64 Tstar = none ? ~0ull : (all ? 0ull : (pref << rb));

    // ---- output: wave B writes this block's 1/16 slice from registers ----
    if (owave) {
        #pragma unroll
        for (int c = 0; c < 4; ++c) {
            int i4 = c * BLK + tid;            // int4 index, this thread's chunk c
            int i  = i4 << 2;                  // element index
            u64 P0 = ((u64)key[c * 4 + 0] << 14) | (unsigned)(NTOK - 1 - (i + 0));
            u64 P1 = ((u64)key[c * 4 + 1] << 14) | (unsigned)(NTOK - 1 - (i + 1));
            u64 P2 = ((u64)key[c * 4 + 2] << 14) | (unsigned)(NTOK - 1 - (i + 2));
            u64 P3 = ((u64)key[c * 4 + 3] << 14) | (unsigned)(NTOK - 1 - (i + 3));
            int4 v;
            v.x = (P0 >= Tstar) ? c4[c].x : t4[c].x;
            v.y = (P1 >= Tstar) ? c4[c].y : t4[c].y;
            v.z = (P2 >= Tstar) ? c4[c].z : t4[c].z;
            v.w = (P3 >= Tstar) ? c4[c].w : t4[c].w;
            ((int4*)out0)[i4] = v;
            int tt = i & 4095;                 // = 4*tid; row = c
            *(int4*)(out1 + c * SQ + (SQ - TQ) + tt) = v;   // plane 0 window
            *(int4*)(out1 + BQ * SQ + c * SQ + tt) = v;     // plane 1 window
        }
    }
}

extern "C" void kernel_launch(void* const* d_in, const int* in_sizes, int n_in,
                              void* d_out, int out_size, void* d_ws, size_t ws_size,
                              hipStream_t stream) {
    const int*   tok    = (const int*)d_in[0];   // tokens          [4,4096]
    const int*   bids   = (const int*)d_in[1];   // batch_input_ids [2,4,8192]
    const int*   cand   = (const int*)d_in[2];   // candidate_tokens[4,4096]
    const float* scores = (const float*)d_in[3]; // candidate_scores[4,4096]
    const int*   kptr   = (const int*)d_in[4];   // unmask_count scalar

    int* out0 = (int*)d_out;        // updated_tokens, 16384 ints
    int* out1 = out0 + NTOK;        // upd, 65536 ints

    token_update_kernel<<<NBLK, BLK, 0, stream>>>(
        scores, cand, tok, bids, kptr, out0, out1);
}